// Round 8
// baseline (449.186 us; speedup 1.0000x reference)
//
#include <hip/hip_runtime.h>
#include <hip/hip_bf16.h>
#include <cstdint>

typedef __attribute__((ext_vector_type(8))) short short8;     // 8 bf16 frag (4 VGPRs)
typedef __attribute__((ext_vector_type(16))) float f32x16;    // 32x32 accumulator
typedef unsigned short us;

#define BIN_SHIFT 8
#define BIN_NODES 256
#define CAPB 6144    // per-bin capacity (mean 4092, +32 sigma)
#define EPB 4096     // edges per binA block

__device__ __forceinline__ float bflo(uint32_t u) { return __builtin_bit_cast(float, u << 16); }
__device__ __forceinline__ float bfhi(uint32_t u) { return __builtin_bit_cast(float, u & 0xffff0000u); }

__device__ __forceinline__ us f32_to_bf16_rne(float f) {
  uint32_t u = __builtin_bit_cast(uint32_t, f);
  u += 0x7fffu + ((u >> 16) & 1u);
  return (us)(u >> 16);
}

// split f32 into truncated-bf16 hi + bf16 lo (residual); hi+lo ~= f to ~2^-16 rel
__device__ __forceinline__ void split2(float f, us& h, us& l) {
  uint32_t u = __builtin_bit_cast(uint32_t, f);
  h = (us)(u >> 16);
  float fh = __builtin_bit_cast(float, u & 0xffff0000u);
  float r = f - fh;  // exact
  l = (us)(__builtin_bit_cast(uint32_t, r) >> 16);
}

// ---------------- prep: weights + init + global-atomic degree count ----------------------------
// blocks 0..127: split W1/W2 -> hi/lo transposed
// blocks 128..159: fold Wp1@Wp2 -> Wc hi/lo
// block 160: gcur[512]=0, hbuf zero row, bc fold
// blocks 161..: per-edge atomicAdd(deg[dst],1)  (deg pre-zeroed by memset; 400KB, L2-resident)
__global__ void k_prep(const float* __restrict__ W1, const float* __restrict__ W2,
                       const float* __restrict__ Wp1, const float* __restrict__ Wp2,
                       const float* __restrict__ bp1, const float* __restrict__ bp2,
                       us* __restrict__ Wt1h, us* __restrict__ Wt1l,
                       us* __restrict__ Wt2h, us* __restrict__ Wt2l,
                       us* __restrict__ Wch, us* __restrict__ Wcl, float* __restrict__ bc,
                       int* __restrict__ gcur, int* __restrict__ hzero,
                       const int* __restrict__ dst, int* __restrict__ deg, int E) {
  int blk = blockIdx.x, tid = threadIdx.x;
  if (blk < 128) {
    const float* W = (blk < 64) ? W1 : W2;
    us* Wh = (blk < 64) ? Wt1h : Wt2h;
    us* Wl = (blk < 64) ? Wt1l : Wt2l;
    int idx = (blk & 63) * 256 + tid;   // 16384
    int k = idx >> 7, n = idx & 127;
    us h, l;
    split2(W[idx], h, l);
    Wh[n * 128 + k] = h;
    Wl[n * 128 + k] = l;
  } else if (blk < 160) {
    int idx = (blk - 128) * 256 + tid;  // 8192
    int k = idx >> 6, j = idx & 63;
    float acc = 0.f;
    for (int t = 0; t < 128; ++t) acc += Wp1[k * 128 + t] * Wp2[t * 64 + j];
    us h, l;
    split2(acc, h, l);
    Wch[j * 128 + k] = h;
    Wcl[j * 128 + k] = l;
  } else if (blk == 160) {
    gcur[tid] = 0;
    gcur[tid + 256] = 0;
    if (tid < 64) {
      hzero[tid] = 0;  // zero dummy row at hbuf[N]
      float acc = bp2[tid];
      for (int t = 0; t < 128; ++t) acc += bp1[t] * Wp2[t * 64 + tid];
      bc[tid] = acc;
    }
  } else {
    int e0 = (blk - 161) * EPB;
    int ne = min(EPB, E - e0);
    for (int i = tid; i < ne; i += 256) atomicAdd(&deg[dst[e0 + i]], 1);
  }
}

// ---------------- pass A: bin (dst,src) pairs by dst>>8 + dis tail blocks ----------------------
__global__ __launch_bounds__(256) void k_binA(
    const int* __restrict__ src, const int* __restrict__ dst,
    uint2* __restrict__ binbuf, int* __restrict__ gcur,
    const int* __restrict__ deg, float* __restrict__ dis,
    int E, int nbins, int ablocks, int N) {
  if ((int)blockIdx.x >= ablocks) {
    // dis tail: one streaming pass (needs deg, complete after prep)
    int i = ((int)blockIdx.x - ablocks) * 256 + (int)threadIdx.x;
    if (i < N) dis[i] = rsqrtf((float)(deg[i] + 1));
    return;
  }
  __shared__ uint2 stage[EPB];                       // 32 KB
  __shared__ int cnt[512], base[512], cur[512], gbase[512];
  int tid = threadIdx.x;
  int e0 = blockIdx.x * EPB;
  int ne = min(EPB, E - e0);
  if (ne <= 0) return;
  cnt[tid] = 0; cnt[tid + 256] = 0;
  __syncthreads();
  for (int i = tid; i < ne; i += 256) atomicAdd(&cnt[dst[e0 + i] >> BIN_SHIFT], 1);
  __syncthreads();
  // exclusive scan cnt[512] -> base (wave 0, 8 chunks of 64)
  if (tid < 64) {
    int carry = 0;
#pragma unroll
    for (int c = 0; c < 8; ++c) {
      int v = cnt[c * 64 + tid];
      int incl = v;
#pragma unroll
      for (int off = 1; off < 64; off <<= 1) {
        int t = __shfl_up(incl, off, 64);
        if (tid >= off) incl += t;
      }
      base[c * 64 + tid] = carry + incl - v;
      carry += __shfl(incl, 63, 64);
    }
  }
  __syncthreads();
  for (int b = tid; b < nbins; b += 256)
    if (cnt[b] > 0) gbase[b] = atomicAdd(&gcur[b], cnt[b]);
  cur[tid] = base[tid]; cur[tid + 256] = base[tid + 256];
  __syncthreads();
  for (int i = tid; i < ne; i += 256) {
    int d = dst[e0 + i], s = src[e0 + i];
    int p = atomicAdd(&cur[d >> BIN_SHIFT], 1);
    stage[p] = make_uint2((unsigned)d, (unsigned)s);
  }
  __syncthreads();
  for (int i = tid; i < ne; i += 256) {
    uint2 en = stage[i];
    int b = en.x >> BIN_SHIFT;
    int gi = gbase[b] + (i - base[b]);
    if (gi < CAPB) binbuf[(size_t)b * CAPB + gi] = en;
  }
}

// ---------------- merged dispatch: passB-lite (blocks < nbins)  ∪  gemm1 (blocks >= nbins) -----
// passB-lite: hist comes straight from deg[] (no first binbuf pass, no count atomics);
//             start/col fill via one LDS-scatter pass over binbuf.
// gemm1: hbuf[row][128] = rne_bf16(dis[row]*(x @ W1)); x staged rne-bf16, W hi+lo.
// Independent inputs (passB: binbuf/gcur/deg; gemm1: x/Wt1/dis) -> CUs overlap the two phases.
__global__ __launch_bounds__(256) void k_pg(
    const uint2* __restrict__ binbuf, const int* __restrict__ gcur,
    const int* __restrict__ deg, int* __restrict__ start, int* __restrict__ col,
    const float* __restrict__ A, const us* __restrict__ Wh, const us* __restrict__ Wl,
    const float* __restrict__ dis, us* __restrict__ out_bf16,
    int N, int nbins, int ntiles) {
  __shared__ int lds[6913];                          // 27.7 KB union
  int tid = threadIdx.x;
  if ((int)blockIdx.x < nbins) {
    // ---- passB-lite ----
    int b = blockIdx.x;
    int* hist = lds;            // 256
    int* lstart = lds + 256;    // 256
    int* cur = lds + 512;       // 256
    int* colstage = lds + 768;  // 6144
    int node0 = b << BIN_SHIFT;
    int cnt = min(gcur[b], CAPB);
    int node = node0 + tid;
    hist[tid] = (node < N) ? deg[node] : 0;
    __syncthreads();
    if (tid < 64) {
      // binbase = sum of capped counts of previous bins
      int s = 0;
      for (int i = tid; i < b; i += 64) s += min(gcur[i], CAPB);
#pragma unroll
      for (int off = 32; off; off >>= 1) s += __shfl_xor(s, off, 64);
      if (tid == 0) lds[6912] = s;
      // exclusive scan hist[256] -> lstart (4 chunks of 64)
      int carry = 0;
#pragma unroll
      for (int c = 0; c < 4; ++c) {
        int v = hist[c * 64 + tid];
        int incl = v;
#pragma unroll
        for (int off = 1; off < 64; off <<= 1) {
          int t = __shfl_up(incl, off, 64);
          if (tid >= off) incl += t;
        }
        lstart[c * 64 + tid] = carry + incl - v;
        carry += __shfl(incl, 63, 64);
      }
    }
    __syncthreads();
    int binbase = lds[6912];
    if (node < N) start[node] = binbase + lstart[tid];
    cur[tid] = lstart[tid];
    __syncthreads();
    const uint2* bp = binbuf + (size_t)b * CAPB;
    for (int i = tid; i < cnt; i += 256) {
      uint2 en = bp[i];
      int p = atomicAdd(&cur[en.x & (BIN_NODES - 1)], 1);
      colstage[p] = (int)en.y;
    }
    __syncthreads();
    for (int i = tid; i < cnt; i += 256) col[binbase + i] = colstage[i];
  } else {
    // ---- gemm1 ----
    us* As = (us*)lds;                               // 32*136 us = 8704 B
    int wave = tid >> 6, lane = tid & 63;
    int n0 = wave * 32;
    int nn = n0 + (lane & 31);
    int khalf = (lane >> 5) * 8;
    int m = lane & 31;

    short8 bh[8], bl[8];
#pragma unroll
    for (int c = 0; c < 8; ++c) {
      bh[c] = *(const short8*)&Wh[nn * 128 + c * 16 + khalf];
      bl[c] = *(const short8*)&Wl[nn * 128 + c * 16 + khalf];
    }

    int t0 = (int)blockIdx.x - nbins;
    int nstride = (int)gridDim.x - nbins;
    for (int t = t0; t < ntiles; t += nstride) {
      int row0 = t * 32;
      __syncthreads();
      for (int j = tid; j < 1024; j += 256) {
        int r = j >> 5, c = j & 31;
        int row = row0 + r;
        float4 v = make_float4(0.f, 0.f, 0.f, 0.f);
        if (row < N) v = *(const float4*)&A[(size_t)row * 128 + c * 4];
        *(ushort4*)&As[r * 136 + c * 4] = make_ushort4(
            f32_to_bf16_rne(v.x), f32_to_bf16_rne(v.y),
            f32_to_bf16_rne(v.z), f32_to_bf16_rne(v.w));
      }
      __syncthreads();

      f32x16 acc = {};
#pragma unroll
      for (int c = 0; c < 8; ++c) {
        short8 ah = *(const short8*)&As[m * 136 + c * 16 + khalf];
        acc = __builtin_amdgcn_mfma_f32_32x32x16_bf16(ah, bh[c], acc, 0, 0, 0);
        acc = __builtin_amdgcn_mfma_f32_32x32x16_bf16(ah, bl[c], acc, 0, 0, 0);
      }

      int colo = n0 + (lane & 31);
      int rbase = row0 + 4 * (lane >> 5);
#pragma unroll
      for (int reg = 0; reg < 16; ++reg) {
        int row = rbase + (reg & 3) + 8 * (reg >> 2);
        if (row < N) {
          float v = acc[reg] * dis[row];
          out_bf16[(size_t)row * 128 + colo] = f32_to_bf16_rne(v);
        }
      }
    }
  }
}

// ---------------- layer-2 GEMM: hbuf[row][128] = rne_bf16(dis[row] * (act @ W2)) ----------------
__global__ __launch_bounds__(256) void k_gemm2(
    const us* __restrict__ A, const us* __restrict__ Wh,
    const us* __restrict__ Wl, const float* __restrict__ dis,
    us* __restrict__ out_bf16, int N, int ntiles) {
  __shared__ us As[32 * 136];
  int tid = threadIdx.x;
  int wave = tid >> 6, lane = tid & 63;
  int n0 = wave * 32;
  int nn = n0 + (lane & 31);
  int khalf = (lane >> 5) * 8;
  int m = lane & 31;

  short8 bh[8], bl[8];
#pragma unroll
  for (int c = 0; c < 8; ++c) {
    bh[c] = *(const short8*)&Wh[nn * 128 + c * 16 + khalf];
    bl[c] = *(const short8*)&Wl[nn * 128 + c * 16 + khalf];
  }

  for (int t = blockIdx.x; t < ntiles; t += gridDim.x) {
    int row0 = t * 32;
    __syncthreads();
    for (int j = tid; j < 512; j += 256) {
      int r = j >> 4, c = j & 15;
      int row = row0 + r;
      uint4 v = make_uint4(0u, 0u, 0u, 0u);
      if (row < N) v = *(const uint4*)&A[(size_t)row * 128 + c * 8];
      *(uint4*)&As[r * 136 + c * 8] = v;
    }
    __syncthreads();

    f32x16 acc = {};
#pragma unroll
    for (int c = 0; c < 8; ++c) {
      short8 ah = *(const short8*)&As[m * 136 + c * 16 + khalf];
      acc = __builtin_amdgcn_mfma_f32_32x32x16_bf16(ah, bh[c], acc, 0, 0, 0);
      acc = __builtin_amdgcn_mfma_f32_32x32x16_bf16(ah, bl[c], acc, 0, 0, 0);
    }

    int col = n0 + (lane & 31);
    int rbase = row0 + 4 * (lane >> 5);
#pragma unroll
    for (int reg = 0; reg < 16; ++reg) {
      int row = rbase + (reg & 3) + 8 * (reg >> 2);
      if (row < N) {
        float v = acc[reg] * dis[row];
        out_bf16[(size_t)row * 128 + col] = f32_to_bf16_rne(v);
      }
    }
  }
}

// ---------------- gather-aggregate (bf16 in) + fused finalize -> bf16 out ----------------
// One 64-lane wave per node (4B = 2 channels per lane), 8 waves/block. col entries preloaded
// into one register and broadcast via readlane (scalar base addressing, col load off critical
// path). Lanes past deg point at the zeroed dummy row at index N (L1-hot), so the 8-chunk loop
// is uniform with no tail and 8 independent gathers in flight per wave.
__global__ __launch_bounds__(512) void k_gather(
    const us* __restrict__ h, us* __restrict__ o,
    const int* __restrict__ start, const int* __restrict__ deg,
    const int* __restrict__ col, const float* __restrict__ dis,
    const float* __restrict__ bias, int N) {
  int wave = threadIdx.x >> 6, lane = threadIdx.x & 63;
  int node = blockIdx.x * 8 + wave;
  if (node >= N) return;
  const uint32_t* h1 = (const uint32_t*)h;
  uint32_t u = h1[(size_t)node * 64 + lane];     // self row
  float a0 = bflo(u), b0 = bfhi(u);
  float a1 = 0.f, b1 = 0.f, a2 = 0.f, b2 = 0.f, a3 = 0.f, b3 = 0.f;
  float a4 = 0.f, b4 = 0.f, a5 = 0.f, b5 = 0.f, a6 = 0.f, b6 = 0.f, a7 = 0.f, b7 = 0.f;
  int e0 = start[node];
  int dg = deg[node];
  int myc = (lane < dg) ? col[e0 + lane] : N;    // N = zero row (dummy)
  int dgm = min(dg, 64);
  for (int k = 0; k < dgm; k += 8) {
    int c0 = __builtin_amdgcn_readlane(myc, k);
    int c1 = __builtin_amdgcn_readlane(myc, k + 1);
    int c2 = __builtin_amdgcn_readlane(myc, k + 2);
    int c3 = __builtin_amdgcn_readlane(myc, k + 3);
    int c4 = __builtin_amdgcn_readlane(myc, k + 4);
    int c5 = __builtin_amdgcn_readlane(myc, k + 5);
    int c6 = __builtin_amdgcn_readlane(myc, k + 6);
    int c7 = __builtin_amdgcn_readlane(myc, k + 7);
    uint32_t u0 = h1[(size_t)c0 * 64 + lane];
    uint32_t u1 = h1[(size_t)c1 * 64 + lane];
    uint32_t u2 = h1[(size_t)c2 * 64 + lane];
    uint32_t u3 = h1[(size_t)c3 * 64 + lane];
    uint32_t u4 = h1[(size_t)c4 * 64 + lane];
    uint32_t u5 = h1[(size_t)c5 * 64 + lane];
    uint32_t u6 = h1[(size_t)c6 * 64 + lane];
    uint32_t u7 = h1[(size_t)c7 * 64 + lane];
    a0 += bflo(u0); b0 += bfhi(u0);
    a1 += bflo(u1); b1 += bfhi(u1);
    a2 += bflo(u2); b2 += bfhi(u2);
    a3 += bflo(u3); b3 += bfhi(u3);
    a4 += bflo(u4); b4 += bfhi(u4);
    a5 += bflo(u5); b5 += bfhi(u5);
    a6 += bflo(u6); b6 += bfhi(u6);
    a7 += bflo(u7); b7 += bfhi(u7);
  }
  // extremely rare deg > 64 fallback (Poisson mean 16)
  for (int e = e0 + 64; e < e0 + dg; ++e) {
    uint32_t u0 = h1[(size_t)col[e] * 64 + lane];
    a0 += bflo(u0); b0 += bfhi(u0);
  }
  float sc = dis[node];
  float2 bb = ((const float2*)bias)[lane];
  float ax = ((a0 + a1) + (a2 + a3)) + ((a4 + a5) + (a6 + a7));
  float ay = ((b0 + b1) + (b2 + b3)) + ((b4 + b5) + (b6 + b7));
  float rx = fmaxf(ax * sc + bb.x, 0.f);
  float ry = fmaxf(ay * sc + bb.y, 0.f);
  ((uint32_t*)o)[(size_t)node * 64 + lane] =
      ((uint32_t)f32_to_bf16_rne(ry) << 16) | f32_to_bf16_rne(rx);
}

// ---------------- head: out = log_softmax(act @ Wc + bc) via MFMA, fused softmax ----------------
__global__ __launch_bounds__(256) void k_head_mfma(
    const us* __restrict__ act, const us* __restrict__ Wch,
    const us* __restrict__ Wcl, const float* __restrict__ bc,
    float* __restrict__ out, int N) {
  __shared__ us As[64 * 136];
  __shared__ float red[2][2][64];
  int tid = threadIdx.x;
  int wave = tid >> 6, lane = tid & 63;
  int rt = wave >> 1, ct = wave & 1;
  int colj = ct * 32 + (lane & 31);
  int khalf = (lane >> 5) * 8;
  int m = lane & 31;

  short8 bh[8], bl[8];
#pragma unroll
  for (int c = 0; c < 8; ++c) {
    bh[c] = *(const short8*)&Wch[colj * 128 + c * 16 + khalf];
    bl[c] = *(const short8*)&Wcl[colj * 128 + c * 16 + khalf];
  }

  int row0 = blockIdx.x * 64;
  for (int j = tid; j < 1024; j += 256) {
    int r = j >> 4, c = j & 15;
    int row = row0 + r;
    uint4 v = make_uint4(0u, 0u, 0u, 0u);
    if (row < N) v = *(const uint4*)&act[(size_t)row * 128 + c * 8];
    *(uint4*)&As[r * 136 + c * 8] = v;
  }
  __syncthreads();

  f32x16 acc = {};
  int mrow = rt * 32 + m;
#pragma unroll
  for (int c = 0; c < 8; ++c) {
    short8 ah = *(const short8*)&As[mrow * 136 + c * 16 + khalf];
    acc = __builtin_amdgcn_mfma_f32_32x32x16_bf16(ah, bh[c], acc, 0, 0, 0);
    acc = __builtin_amdgcn_mfma_f32_32x32x16_bf16(ah, bl[c], acc, 0, 0, 0);
  }

  float bcv = bc[colj];
  float lg[16], mx[16];
#pragma unroll
  for (int reg = 0; reg < 16; ++reg) {
    lg[reg] = acc[reg] + bcv;
    float v = lg[reg];
#pragma unroll
    for (int off = 16; off > 0; off >>= 1) v = fmaxf(v, __shfl_xor(v, off, 32));
    mx[reg] = v;
  }
  if ((lane & 31) == 0) {
#pragma unroll
    for (int reg = 0; reg < 16; ++reg) {
      int rl = rt * 32 + (reg & 3) + 8 * (reg >> 2) + 4 * (lane >> 5);
      red[0][ct][rl] = mx[reg];
    }
  }
  __syncthreads();

  float ex[16], sm[16];
#pragma unroll
  for (int reg = 0; reg < 16; ++reg) {
    int rl = rt * 32 + (reg & 3) + 8 * (reg >> 2) + 4 * (lane >> 5);
    float rmax = fmaxf(red[0][0][rl], red[0][1][rl]);
    ex[reg] = lg[reg] - rmax;
    float v = expf(ex[reg]);
#pragma unroll
    for (int off = 16; off > 0; off >>= 1) v += __shfl_xor(v, off, 32);
    sm[reg] = v;
  }
  if ((lane & 31) == 0) {
#pragma unroll
    for (int reg = 0; reg < 16; ++reg) {
      int rl = rt * 32 + (reg & 3) + 8 * (reg >> 2) + 4 * (lane >> 5);
      red[1][ct][rl] = sm[reg];
    }
  }
  __syncthreads();

#pragma unroll
  for (int reg = 0; reg < 16; ++reg) {
    int rl = rt * 32 + (reg & 3) + 8 * (reg >> 2) + 4 * (lane >> 5);
    int row = row0 + rl;
    if (row < N) {
      float total = red[1][0][rl] + red[1][1][rl];
      out[(size_t)row * 64 + colj] = ex[reg] - logf(total);
    }
  }
}

extern "C" void kernel_launch(void* const* d_in, const int* in_sizes, int n_in,
                              void* d_out, int out_size, void* d_ws, size_t ws_size,
                              hipStream_t stream) {
  const float* x   = (const float*)d_in[0];
  const int*   ei  = (const int*)d_in[1];
  const float* W1  = (const float*)d_in[2];
  const float* b1  = (const float*)d_in[3];
  const float* W2  = (const float*)d_in[4];
  const float* b2  = (const float*)d_in[5];
  const float* Wp1 = (const float*)d_in[6];
  const float* bp1 = (const float*)d_in[7];
  const float* Wp2 = (const float*)d_in[8];
  const float* bp2 = (const float*)d_in[9];
  float* out = (float*)d_out;

  int N = in_sizes[0] / 128;
  int E = in_sizes[1] / 2;
  const int* src = ei;
  const int* dst = ei + E;
  int nbins = (N + BIN_NODES - 1) >> BIN_SHIFT;

  // workspace layout (int granularity)
  float* dis   = (float*)d_ws;                    // N
  int*   deg   = (int*)(dis + N);                 // N (memset to 0)
  int*   start = deg + N;                         // N
  int*   col   = start + N;                       // E
  int*   gcur  = col + ((E + 3) & ~3);            // 512 (zeroed by k_prep)
  us* Wt1h = (us*)(gcur + 512);                   // 16384 each
  us* Wt1l = Wt1h + 16384;
  us* Wt2h = Wt1l + 16384;
  us* Wt2l = Wt2h + 16384;
  us* Wch  = Wt2l + 16384;                        // 8192
  us* Wcl  = Wch + 8192;                          // 8192
  float* bc = (float*)(Wcl + 8192);               // 64 (+pad)
  uint2* binbuf = (uint2*)(bc + 80);              // nbins*CAPB uint2 (~19.2 MB)
  us* hbuf = (us*)(binbuf + (size_t)nbins * CAPB);  // (N+1)*128 bf16 (row N = zero, by k_prep)
  us* act  = hbuf + (size_t)(N + 1) * 128;          // N*128 bf16 = 25.6 MB

  hipMemsetAsync(deg, 0, N * sizeof(int), stream);

  int ablocks = (E + EPB - 1) / EPB;
  int dblocks = (N + 255) / 256;
  int ntiles = (N + 31) / 32;
  int gemm_grid = ntiles < 1024 ? ntiles : 1024;
  int agblocks = (N + 7) / 8;
  int hblocks = (N + 63) / 64;

  // prep: weights + init + global-atomic degree count
  k_prep<<<161 + ablocks, 256, 0, stream>>>(W1, W2, Wp1, Wp2, bp1, bp2,
                                            Wt1h, Wt1l, Wt2h, Wt2l, Wch, Wcl, bc,
                                            gcur, (int*)(hbuf + (size_t)N * 128),
                                            dst, deg, E);
  // binA: edge binning + dis tail
  k_binA<<<ablocks + dblocks, 256, 0, stream>>>(src, dst, binbuf, gcur, deg, dis,
                                                E, nbins, ablocks, N);
  // merged: passB-lite (CSR finalize) || gemm1 (x @ W1)
  k_pg<<<nbins + gemm_grid, 256, 0, stream>>>(binbuf, gcur, deg, start, col,
                                              x, Wt1h, Wt1l, dis, hbuf,
                                              N, nbins, ntiles);
  // layer 1 aggregate
  k_gather<<<agblocks, 512, 0, stream>>>(hbuf, act, start, deg, col, dis, b1, N);
  // layer 2
  k_gemm2<<<gemm_grid, 256, 0, stream>>>(act, Wt2h, Wt2l, dis, hbuf, N, ntiles);
  k_gather<<<agblocks, 512, 0, stream>>>(hbuf, act, start, deg, col, dis, b2, N);
  // folded head (MFMA + fused log_softmax)
  k_head_mfma<<<hblocks, 256, 0, stream>>>(act, Wch, Wcl, bc, out, N);
}

// Round 9
// 399.341 us; speedup vs baseline: 1.1248x; 1.1248x over previous
//
#include <hip/hip_runtime.h>
#include <hip/hip_bf16.h>
#include <cstdint>

typedef __attribute__((ext_vector_type(8))) short short8;     // 8 bf16 frag (4 VGPRs)
typedef __attribute__((ext_vector_type(16))) float f32x16;    // 32x32 accumulator
typedef unsigned short us;

#define BIN_SHIFT 8
#define BIN_NODES 256
#define CAPB 6144    // per-bin capacity (mean 4092, +32 sigma)
#define EPB 4096     // edges per binA block

__device__ __forceinline__ float bflo(uint32_t u) { return __builtin_bit_cast(float, u << 16); }
__device__ __forceinline__ float bfhi(uint32_t u) { return __builtin_bit_cast(float, u & 0xffff0000u); }

__device__ __forceinline__ us f32_to_bf16_rne(float f) {
  uint32_t u = __builtin_bit_cast(uint32_t, f);
  u += 0x7fffu + ((u >> 16) & 1u);
  return (us)(u >> 16);
}

// split f32 into truncated-bf16 hi + bf16 lo (residual); hi+lo ~= f to ~2^-16 rel
__device__ __forceinline__ void split2(float f, us& h, us& l) {
  uint32_t u = __builtin_bit_cast(uint32_t, f);
  h = (us)(u >> 16);
  float fh = __builtin_bit_cast(float, u & 0xffff0000u);
  float r = f - fh;  // exact
  l = (us)(__builtin_bit_cast(uint32_t, r) >> 16);
}

// ---------------- merged dispatch: binA (blocks < ablocks) ∥ weight prep (blocks >= ablocks) ----
// binA: bin (dst,src) by dst>>8 with dense batched appends; entries packed to 32b:
//       (dst&255)<<24 | src   (valid: src < 2^24, BIN_NODES=256).  gcur zeroed by memset.
// prep: split W1/W2 hi/lo; fold head Wp1@Wp2 + bc; zero hbuf dummy row.
// Inputs are disjoint (edges vs weights) -> CUs overlap the two phases.
__global__ __launch_bounds__(256) void k_ba(
    const int* __restrict__ src, const int* __restrict__ dst,
    uint32_t* __restrict__ binbuf, int* __restrict__ gcur, int E, int nbins, int ablocks,
    const float* __restrict__ W1, const float* __restrict__ W2,
    const float* __restrict__ Wp1, const float* __restrict__ Wp2,
    const float* __restrict__ bp1, const float* __restrict__ bp2,
    us* __restrict__ Wt1h, us* __restrict__ Wt1l,
    us* __restrict__ Wt2h, us* __restrict__ Wt2l,
    us* __restrict__ Wch, us* __restrict__ Wcl, float* __restrict__ bc,
    int* __restrict__ hzero) {
  int tid = threadIdx.x;
  if ((int)blockIdx.x >= ablocks) {
    int blk = (int)blockIdx.x - ablocks;   // 0..160
    if (blk < 128) {
      const float* W = (blk < 64) ? W1 : W2;
      us* Wh = (blk < 64) ? Wt1h : Wt2h;
      us* Wl = (blk < 64) ? Wt1l : Wt2l;
      int idx = (blk & 63) * 256 + tid;   // 16384
      int k = idx >> 7, n = idx & 127;
      us h, l;
      split2(W[idx], h, l);
      Wh[n * 128 + k] = h;
      Wl[n * 128 + k] = l;
    } else if (blk < 160) {
      int idx = (blk - 128) * 256 + tid;  // 8192
      int k = idx >> 6, j = idx & 63;
      float acc = 0.f;
      for (int t = 0; t < 128; ++t) acc += Wp1[k * 128 + t] * Wp2[t * 64 + j];
      us h, l;
      split2(acc, h, l);
      Wch[j * 128 + k] = h;
      Wcl[j * 128 + k] = l;
    } else {
      if (tid < 64) {
        hzero[tid] = 0;  // zero dummy row at hbuf[N]
        float acc = bp2[tid];
        for (int t = 0; t < 128; ++t) acc += bp1[t] * Wp2[t * 64 + tid];
        bc[tid] = acc;
      }
    }
    return;
  }
  // ---- binA ----
  __shared__ uint2 stage[EPB];                       // 32 KB
  __shared__ int cnt[512], base[512], cur[512], gbase[512];
  int e0 = blockIdx.x * EPB;
  int ne = min(EPB, E - e0);
  if (ne <= 0) return;
  cnt[tid] = 0; cnt[tid + 256] = 0;
  __syncthreads();
  for (int i = tid; i < ne; i += 256) atomicAdd(&cnt[dst[e0 + i] >> BIN_SHIFT], 1);
  __syncthreads();
  // exclusive scan cnt[512] -> base (wave 0, 8 chunks of 64)
  if (tid < 64) {
    int carry = 0;
#pragma unroll
    for (int c = 0; c < 8; ++c) {
      int v = cnt[c * 64 + tid];
      int incl = v;
#pragma unroll
      for (int off = 1; off < 64; off <<= 1) {
        int t = __shfl_up(incl, off, 64);
        if (tid >= off) incl += t;
      }
      base[c * 64 + tid] = carry + incl - v;
      carry += __shfl(incl, 63, 64);
    }
  }
  __syncthreads();
  for (int b = tid; b < nbins; b += 256)
    if (cnt[b] > 0) gbase[b] = atomicAdd(&gcur[b], cnt[b]);
  cur[tid] = base[tid]; cur[tid + 256] = base[tid + 256];
  __syncthreads();
  for (int i = tid; i < ne; i += 256) {
    int d = dst[e0 + i], s = src[e0 + i];
    int p = atomicAdd(&cur[d >> BIN_SHIFT], 1);
    stage[p] = make_uint2((unsigned)d, (unsigned)s);
  }
  __syncthreads();
  for (int i = tid; i < ne; i += 256) {
    uint2 en = stage[i];
    int b = en.x >> BIN_SHIFT;
    int gi = gbase[b] + (i - base[b]);
    if (gi < CAPB)
      binbuf[(size_t)b * CAPB + gi] = ((en.x & (BIN_NODES - 1)) << 24) | en.y;
  }
}

// ---------------- pass B: per-bin deg/dis/start + col fill from packed entries ----------------
__global__ __launch_bounds__(256) void k_passB(
    const uint32_t* __restrict__ binbuf, const int* __restrict__ gcur,
    int* __restrict__ deg, float* __restrict__ dis, int* __restrict__ start,
    int* __restrict__ col, int N, int nbins) {
  __shared__ int hist[256], lstart[256], cur[256];
  __shared__ int colstage[CAPB];                     // 24 KB
  __shared__ int binbase_s;
  int b = blockIdx.x, tid = threadIdx.x;
  int node0 = b << BIN_SHIFT;
  int cnt = min(gcur[b], CAPB);
  hist[tid] = 0;
  __syncthreads();
  const uint32_t* bp = binbuf + (size_t)b * CAPB;
  for (int i = tid; i < cnt; i += 256) atomicAdd(&hist[bp[i] >> 24], 1);
  __syncthreads();
  if (tid < 64) {
    // binbase = sum of capped counts of previous bins
    int s = 0;
    for (int i = tid; i < b; i += 64) s += min(gcur[i], CAPB);
#pragma unroll
    for (int off = 32; off; off >>= 1) s += __shfl_xor(s, off, 64);
    if (tid == 0) binbase_s = s;
    // exclusive scan hist[256] -> lstart (4 chunks of 64)
    int carry = 0;
#pragma unroll
    for (int c = 0; c < 4; ++c) {
      int v = hist[c * 64 + tid];
      int incl = v;
#pragma unroll
      for (int off = 1; off < 64; off <<= 1) {
        int t = __shfl_up(incl, off, 64);
        if (tid >= off) incl += t;
      }
      lstart[c * 64 + tid] = carry + incl - v;
      carry += __shfl(incl, 63, 64);
    }
  }
  __syncthreads();
  int binbase = binbase_s;
  {
    int node = node0 + tid;
    if (node < N) {
      int dg = hist[tid];
      deg[node] = dg;
      dis[node] = rsqrtf((float)(dg + 1));
      start[node] = binbase + lstart[tid];
    }
  }
  cur[tid] = lstart[tid];
  __syncthreads();
  for (int i = tid; i < cnt; i += 256) {
    uint32_t en = bp[i];
    int p = atomicAdd(&cur[en >> 24], 1);
    colstage[p] = (int)(en & 0xFFFFFFu);
  }
  __syncthreads();
  for (int i = tid; i < cnt; i += 256) col[binbase + i] = colstage[i];
}

// ---------------- layer-1 GEMM: hbuf[row][128] = rne_bf16(dis[row] * (x @ W1)) ----------------
// x staged rne-bf16; W hi+lo. Split even/odd accumulator chains (2x ILP on MFMA).
__global__ __launch_bounds__(256) void k_gemm1(
    const float* __restrict__ A, const us* __restrict__ Wh,
    const us* __restrict__ Wl, const float* __restrict__ dis,
    us* __restrict__ out_bf16, int N, int ntiles) {
  __shared__ us As[32 * 136];
  int tid = threadIdx.x;
  int wave = tid >> 6, lane = tid & 63;
  int n0 = wave * 32;
  int nn = n0 + (lane & 31);
  int khalf = (lane >> 5) * 8;
  int m = lane & 31;

  short8 bh[8], bl[8];
#pragma unroll
  for (int c = 0; c < 8; ++c) {
    bh[c] = *(const short8*)&Wh[nn * 128 + c * 16 + khalf];
    bl[c] = *(const short8*)&Wl[nn * 128 + c * 16 + khalf];
  }

  for (int t = blockIdx.x; t < ntiles; t += gridDim.x) {
    int row0 = t * 32;
    __syncthreads();
    for (int j = tid; j < 1024; j += 256) {
      int r = j >> 5, c = j & 31;
      int row = row0 + r;
      float4 v = make_float4(0.f, 0.f, 0.f, 0.f);
      if (row < N) v = *(const float4*)&A[(size_t)row * 128 + c * 4];
      *(ushort4*)&As[r * 136 + c * 4] = make_ushort4(
          f32_to_bf16_rne(v.x), f32_to_bf16_rne(v.y),
          f32_to_bf16_rne(v.z), f32_to_bf16_rne(v.w));
    }
    __syncthreads();

    f32x16 acc0 = {}, acc1 = {};
#pragma unroll
    for (int c = 0; c < 4; ++c) {
      short8 ae = *(const short8*)&As[m * 136 + (2 * c) * 16 + khalf];
      short8 ao = *(const short8*)&As[m * 136 + (2 * c + 1) * 16 + khalf];
      acc0 = __builtin_amdgcn_mfma_f32_32x32x16_bf16(ae, bh[2 * c], acc0, 0, 0, 0);
      acc1 = __builtin_amdgcn_mfma_f32_32x32x16_bf16(ao, bh[2 * c + 1], acc1, 0, 0, 0);
      acc0 = __builtin_amdgcn_mfma_f32_32x32x16_bf16(ae, bl[2 * c], acc0, 0, 0, 0);
      acc1 = __builtin_amdgcn_mfma_f32_32x32x16_bf16(ao, bl[2 * c + 1], acc1, 0, 0, 0);
    }

    int col = n0 + (lane & 31);
    int rbase = row0 + 4 * (lane >> 5);
#pragma unroll
    for (int reg = 0; reg < 16; ++reg) {
      int row = rbase + (reg & 3) + 8 * (reg >> 2);
      if (row < N) {
        float v = (acc0[reg] + acc1[reg]) * dis[row];
        out_bf16[(size_t)row * 128 + col] = f32_to_bf16_rne(v);
      }
    }
  }
}

// ---------------- layer-2 GEMM: hbuf[row][128] = rne_bf16(dis[row] * (act @ W2)) ----------------
__global__ __launch_bounds__(256) void k_gemm2(
    const us* __restrict__ A, const us* __restrict__ Wh,
    const us* __restrict__ Wl, const float* __restrict__ dis,
    us* __restrict__ out_bf16, int N, int ntiles) {
  __shared__ us As[32 * 136];
  int tid = threadIdx.x;
  int wave = tid >> 6, lane = tid & 63;
  int n0 = wave * 32;
  int nn = n0 + (lane & 31);
  int khalf = (lane >> 5) * 8;
  int m = lane & 31;

  short8 bh[8], bl[8];
#pragma unroll
  for (int c = 0; c < 8; ++c) {
    bh[c] = *(const short8*)&Wh[nn * 128 + c * 16 + khalf];
    bl[c] = *(const short8*)&Wl[nn * 128 + c * 16 + khalf];
  }

  for (int t = blockIdx.x; t < ntiles; t += gridDim.x) {
    int row0 = t * 32;
    __syncthreads();
    for (int j = tid; j < 512; j += 256) {
      int r = j >> 4, c = j & 15;
      int row = row0 + r;
      uint4 v = make_uint4(0u, 0u, 0u, 0u);
      if (row < N) v = *(const uint4*)&A[(size_t)row * 128 + c * 8];
      *(uint4*)&As[r * 136 + c * 8] = v;
    }
    __syncthreads();

    f32x16 acc0 = {}, acc1 = {};
#pragma unroll
    for (int c = 0; c < 4; ++c) {
      short8 ae = *(const short8*)&As[m * 136 + (2 * c) * 16 + khalf];
      short8 ao = *(const short8*)&As[m * 136 + (2 * c + 1) * 16 + khalf];
      acc0 = __builtin_amdgcn_mfma_f32_32x32x16_bf16(ae, bh[2 * c], acc0, 0, 0, 0);
      acc1 = __builtin_amdgcn_mfma_f32_32x32x16_bf16(ao, bh[2 * c + 1], acc1, 0, 0, 0);
      acc0 = __builtin_amdgcn_mfma_f32_32x32x16_bf16(ae, bl[2 * c], acc0, 0, 0, 0);
      acc1 = __builtin_amdgcn_mfma_f32_32x32x16_bf16(ao, bl[2 * c + 1], acc1, 0, 0, 0);
    }

    int col = n0 + (lane & 31);
    int rbase = row0 + 4 * (lane >> 5);
#pragma unroll
    for (int reg = 0; reg < 16; ++reg) {
      int row = rbase + (reg & 3) + 8 * (reg >> 2);
      if (row < N) {
        float v = (acc0[reg] + acc1[reg]) * dis[row];
        out_bf16[(size_t)row * 128 + col] = f32_to_bf16_rne(v);
      }
    }
  }
}

// ---------------- gather-aggregate (bf16 in) + fused finalize -> bf16 out ----------------
// One 64-lane wave per node (4B = 2 channels per lane), 8 waves/block. col entries preloaded
// into one register and broadcast via readlane (scalar base addressing, col load off critical
// path). Lanes past deg point at the zeroed dummy row at index N (L1-hot), so the 8-chunk loop
// is uniform with no tail and 8 independent gathers in flight per wave.
__global__ __launch_bounds__(512) void k_gather(
    const us* __restrict__ h, us* __restrict__ o,
    const int* __restrict__ start, const int* __restrict__ deg,
    const int* __restrict__ col, const float* __restrict__ dis,
    const float* __restrict__ bias, int N) {
  int wave = threadIdx.x >> 6, lane = threadIdx.x & 63;
  int node = blockIdx.x * 8 + wave;
  if (node >= N) return;
  const uint32_t* h1 = (const uint32_t*)h;
  uint32_t u = h1[(size_t)node * 64 + lane];     // self row
  float a0 = bflo(u), b0 = bfhi(u);
  float a1 = 0.f, b1 = 0.f, a2 = 0.f, b2 = 0.f, a3 = 0.f, b3 = 0.f;
  float a4 = 0.f, b4 = 0.f, a5 = 0.f, b5 = 0.f, a6 = 0.f, b6 = 0.f, a7 = 0.f, b7 = 0.f;
  int e0 = start[node];
  int dg = deg[node];
  int myc = (lane < dg) ? col[e0 + lane] : N;    // N = zero row (dummy)
  int dgm = min(dg, 64);
  for (int k = 0; k < dgm; k += 8) {
    int c0 = __builtin_amdgcn_readlane(myc, k);
    int c1 = __builtin_amdgcn_readlane(myc, k + 1);
    int c2 = __builtin_amdgcn_readlane(myc, k + 2);
    int c3 = __builtin_amdgcn_readlane(myc, k + 3);
    int c4 = __builtin_amdgcn_readlane(myc, k + 4);
    int c5 = __builtin_amdgcn_readlane(myc, k + 5);
    int c6 = __builtin_amdgcn_readlane(myc, k + 6);
    int c7 = __builtin_amdgcn_readlane(myc, k + 7);
    uint32_t u0 = h1[(size_t)c0 * 64 + lane];
    uint32_t u1 = h1[(size_t)c1 * 64 + lane];
    uint32_t u2 = h1[(size_t)c2 * 64 + lane];
    uint32_t u3 = h1[(size_t)c3 * 64 + lane];
    uint32_t u4 = h1[(size_t)c4 * 64 + lane];
    uint32_t u5 = h1[(size_t)c5 * 64 + lane];
    uint32_t u6 = h1[(size_t)c6 * 64 + lane];
    uint32_t u7 = h1[(size_t)c7 * 64 + lane];
    a0 += bflo(u0); b0 += bfhi(u0);
    a1 += bflo(u1); b1 += bfhi(u1);
    a2 += bflo(u2); b2 += bfhi(u2);
    a3 += bflo(u3); b3 += bfhi(u3);
    a4 += bflo(u4); b4 += bfhi(u4);
    a5 += bflo(u5); b5 += bfhi(u5);
    a6 += bflo(u6); b6 += bfhi(u6);
    a7 += bflo(u7); b7 += bfhi(u7);
  }
  // extremely rare deg > 64 fallback (Poisson mean 16)
  for (int e = e0 + 64; e < e0 + dg; ++e) {
    uint32_t u0 = h1[(size_t)col[e] * 64 + lane];
    a0 += bflo(u0); b0 += bfhi(u0);
  }
  float sc = dis[node];
  float2 bb = ((const float2*)bias)[lane];
  float ax = ((a0 + a1) + (a2 + a3)) + ((a4 + a5) + (a6 + a7));
  float ay = ((b0 + b1) + (b2 + b3)) + ((b4 + b5) + (b6 + b7));
  float rx = fmaxf(ax * sc + bb.x, 0.f);
  float ry = fmaxf(ay * sc + bb.y, 0.f);
  ((uint32_t*)o)[(size_t)node * 64 + lane] =
      ((uint32_t)f32_to_bf16_rne(ry) << 16) | f32_to_bf16_rne(rx);
}

// ---------------- head: out = log_softmax(act @ Wc + bc) via MFMA, fused softmax ----------------
__global__ __launch_bounds__(256) void k_head_mfma(
    const us* __restrict__ act, const us* __restrict__ Wch,
    const us* __restrict__ Wcl, const float* __restrict__ bc,
    float* __restrict__ out, int N) {
  __shared__ us As[64 * 136];
  __shared__ float red[2][2][64];
  int tid = threadIdx.x;
  int wave = tid >> 6, lane = tid & 63;
  int rt = wave >> 1, ct = wave & 1;
  int colj = ct * 32 + (lane & 31);
  int khalf = (lane >> 5) * 8;
  int m = lane & 31;

  short8 bh[8], bl[8];
#pragma unroll
  for (int c = 0; c < 8; ++c) {
    bh[c] = *(const short8*)&Wch[colj * 128 + c * 16 + khalf];
    bl[c] = *(const short8*)&Wcl[colj * 128 + c * 16 + khalf];
  }

  int row0 = blockIdx.x * 64;
  for (int j = tid; j < 1024; j += 256) {
    int r = j >> 4, c = j & 15;
    int row = row0 + r;
    uint4 v = make_uint4(0u, 0u, 0u, 0u);
    if (row < N) v = *(const uint4*)&act[(size_t)row * 128 + c * 8];
    *(uint4*)&As[r * 136 + c * 8] = v;
  }
  __syncthreads();

  f32x16 acc0 = {}, acc1 = {};
  int mrow = rt * 32 + m;
#pragma unroll
  for (int c = 0; c < 4; ++c) {
    short8 ae = *(const short8*)&As[mrow * 136 + (2 * c) * 16 + khalf];
    short8 ao = *(const short8*)&As[mrow * 136 + (2 * c + 1) * 16 + khalf];
    acc0 = __builtin_amdgcn_mfma_f32_32x32x16_bf16(ae, bh[2 * c], acc0, 0, 0, 0);
    acc1 = __builtin_amdgcn_mfma_f32_32x32x16_bf16(ao, bh[2 * c + 1], acc1, 0, 0, 0);
    acc0 = __builtin_amdgcn_mfma_f32_32x32x16_bf16(ae, bl[2 * c], acc0, 0, 0, 0);
    acc1 = __builtin_amdgcn_mfma_f32_32x32x16_bf16(ao, bl[2 * c + 1], acc1, 0, 0, 0);
  }

  float bcv = bc[colj];
  float lg[16], mx[16];
#pragma unroll
  for (int reg = 0; reg < 16; ++reg) {
    lg[reg] = acc0[reg] + acc1[reg] + bcv;
    float v = lg[reg];
#pragma unroll
    for (int off = 16; off > 0; off >>= 1) v = fmaxf(v, __shfl_xor(v, off, 32));
    mx[reg] = v;
  }
  if ((lane & 31) == 0) {
#pragma unroll
    for (int reg = 0; reg < 16; ++reg) {
      int rl = rt * 32 + (reg & 3) + 8 * (reg >> 2) + 4 * (lane >> 5);
      red[0][ct][rl] = mx[reg];
    }
  }
  __syncthreads();

  float ex[16], sm[16];
#pragma unroll
  for (int reg = 0; reg < 16; ++reg) {
    int rl = rt * 32 + (reg & 3) + 8 * (reg >> 2) + 4 * (lane >> 5);
    float rmax = fmaxf(red[0][0][rl], red[0][1][rl]);
    ex[reg] = lg[reg] - rmax;
    float v = expf(ex[reg]);
#pragma unroll
    for (int off = 16; off > 0; off >>= 1) v += __shfl_xor(v, off, 32);
    sm[reg] = v;
  }
  if ((lane & 31) == 0) {
#pragma unroll
    for (int reg = 0; reg < 16; ++reg) {
      int rl = rt * 32 + (reg & 3) + 8 * (reg >> 2) + 4 * (lane >> 5);
      red[1][ct][rl] = sm[reg];
    }
  }
  __syncthreads();

#pragma unroll
  for (int reg = 0; reg < 16; ++reg) {
    int rl = rt * 32 + (reg & 3) + 8 * (reg >> 2) + 4 * (lane >> 5);
    int row = row0 + rl;
    if (row < N) {
      float total = red[1][0][rl] + red[1][1][rl];
      out[(size_t)row * 64 + colj] = ex[reg] - logf(total);
    }
  }
}

extern "C" void kernel_launch(void* const* d_in, const int* in_sizes, int n_in,
                              void* d_out, int out_size, void* d_ws, size_t ws_size,
                              hipStream_t stream) {
  const float* x   = (const float*)d_in[0];
  const int*   ei  = (const int*)d_in[1];
  const float* W1  = (const float*)d_in[2];
  const float* b1  = (const float*)d_in[3];
  const float* W2  = (const float*)d_in[4];
  const float* b2  = (const float*)d_in[5];
  const float* Wp1 = (const float*)d_in[6];
  const float* bp1 = (const float*)d_in[7];
  const float* Wp2 = (const float*)d_in[8];
  const float* bp2 = (const float*)d_in[9];
  float* out = (float*)d_out;

  int N = in_sizes[0] / 128;
  int E = in_sizes[1] / 2;
  const int* src = ei;
  const int* dst = ei + E;
  int nbins = (N + BIN_NODES - 1) >> BIN_SHIFT;

  // workspace layout (int granularity)
  float* dis   = (float*)d_ws;                    // N
  int*   deg   = (int*)(dis + N);                 // N
  int*   start = deg + N;                         // N
  int*   col   = start + N;                       // E
  int*   gcur  = col + ((E + 3) & ~3);            // 512 (zeroed by memset)
  us* Wt1h = (us*)(gcur + 512);                   // 16384 each
  us* Wt1l = Wt1h + 16384;
  us* Wt2h = Wt1l + 16384;
  us* Wt2l = Wt2h + 16384;
  us* Wch  = Wt2l + 16384;                        // 8192
  us* Wcl  = Wch + 8192;                          // 8192
  float* bc = (float*)(Wcl + 8192);               // 64 (+pad)
  uint32_t* binbuf = (uint32_t*)(bc + 80);        // nbins*CAPB packed u32 (~9.6 MB)
  us* hbuf = (us*)(binbuf + (size_t)nbins * CAPB);  // (N+1)*128 bf16 (row N = zero, by k_ba)
  us* act  = hbuf + (size_t)(N + 1) * 128;          // N*128 bf16 = 25.6 MB

  hipMemsetAsync(gcur, 0, 512 * sizeof(int), stream);

  int ablocks = (E + EPB - 1) / EPB;
  int ntiles = (N + 31) / 32;
  int gemm_grid = ntiles < 2048 ? ntiles : 2048;
  int agblocks = (N + 7) / 8;
  int hblocks = (N + 63) / 64;

  // merged: binA (edge binning) ∥ weight prep
  k_ba<<<ablocks + 161, 256, 0, stream>>>(src, dst, binbuf, gcur, E, nbins, ablocks,
                                          W1, W2, Wp1, Wp2, bp1, bp2,
                                          Wt1h, Wt1l, Wt2h, Wt2l, Wch, Wcl, bc,
                                          (int*)(hbuf + (size_t)N * 128));
  k_passB<<<nbins, 256, 0, stream>>>(binbuf, gcur, deg, dis, start, col, N, nbins);

  // layer 1
  k_gemm1<<<gemm_grid, 256, 0, stream>>>(x, Wt1h, Wt1l, dis, hbuf, N, ntiles);
  k_gather<<<agblocks, 512, 0, stream>>>(hbuf, act, start, deg, col, dis, b1, N);
  // layer 2
  k_gemm2<<<gemm_grid, 256, 0, stream>>>(act, Wt2h, Wt2l, dis, hbuf, N, ntiles);
  k_gather<<<agblocks, 512, 0, stream>>>(hbuf, act, start, deg, col, dis, b2, N);
  // folded head (MFMA + fused log_softmax)
  k_head_mfma<<<hblocks, 256, 0, stream>>>(act, Wch, Wcl, bc, out, N);
}

// Round 10
// 373.365 us; speedup vs baseline: 1.2031x; 1.0696x over previous
//
#include <hip/hip_runtime.h>
#include <hip/hip_bf16.h>
#include <cstdint>

typedef __attribute__((ext_vector_type(8))) short short8;     // 8 bf16 frag (4 VGPRs)
typedef __attribute__((ext_vector_type(16))) float f32x16;    // 32x32 accumulator
typedef unsigned short us;

#define BIN_SHIFT 8
#define BIN_NODES 256
#define CAPB 6144    // per-bin capacity (mean 4092, +32 sigma)
#define EPB 4096     // edges per binA block
#define G1GRID 1024  // gemm1 blocks inside k_bg

__device__ __forceinline__ float bflo(uint32_t u) { return __builtin_bit_cast(float, u << 16); }
__device__ __forceinline__ float bfhi(uint32_t u) { return __builtin_bit_cast(float, u & 0xffff0000u); }

__device__ __forceinline__ us f32_to_bf16_rne(float f) {
  uint32_t u = __builtin_bit_cast(uint32_t, f);
  u += 0x7fffu + ((u >> 16) & 1u);
  return (us)(u >> 16);
}

__device__ __forceinline__ float rdlane_f(float v, int l) {
  return __builtin_bit_cast(float, __builtin_amdgcn_readlane(__builtin_bit_cast(int, v), l));
}

// split f32 into truncated-bf16 hi + bf16 lo (residual); hi+lo ~= f to ~2^-16 rel
__device__ __forceinline__ void split2(float f, us& h, us& l) {
  uint32_t u = __builtin_bit_cast(uint32_t, f);
  h = (us)(u >> 16);
  float fh = __builtin_bit_cast(float, u & 0xffff0000u);
  float r = f - fh;  // exact
  l = (us)(__builtin_bit_cast(uint32_t, r) >> 16);
}

// ---------------- merged weight prep + workspace init (runs FIRST) ----------------------------
__global__ void k_prep(const float* __restrict__ W1, const float* __restrict__ W2,
                       const float* __restrict__ Wp1, const float* __restrict__ Wp2,
                       const float* __restrict__ bp1, const float* __restrict__ bp2,
                       us* __restrict__ Wt1h, us* __restrict__ Wt1l,
                       us* __restrict__ Wt2h, us* __restrict__ Wt2l,
                       us* __restrict__ Wch, us* __restrict__ Wcl, float* __restrict__ bc,
                       int* __restrict__ gcur, int* __restrict__ hzero) {
  int blk = blockIdx.x, tid = threadIdx.x;
  if (blk < 128) {
    const float* W = (blk < 64) ? W1 : W2;
    us* Wh = (blk < 64) ? Wt1h : Wt2h;
    us* Wl = (blk < 64) ? Wt1l : Wt2l;
    int idx = (blk & 63) * 256 + tid;   // 16384
    int k = idx >> 7, n = idx & 127;
    us h, l;
    split2(W[idx], h, l);
    Wh[n * 128 + k] = h;
    Wl[n * 128 + k] = l;
  } else if (blk < 160) {
    int idx = (blk - 128) * 256 + tid;  // 8192
    int k = idx >> 6, j = idx & 63;
    float acc = 0.f;
    for (int t = 0; t < 128; ++t) acc += Wp1[k * 128 + t] * Wp2[t * 64 + j];
    us h, l;
    split2(acc, h, l);
    Wch[j * 128 + k] = h;
    Wcl[j * 128 + k] = l;
  } else {
    // workspace init: gcur[512] = 0, hbuf zero row, bc fold
    gcur[tid] = 0;
    gcur[tid + 256] = 0;
    if (tid < 64) {
      hzero[tid] = 0;  // zero dummy row at hbuf[N]
      float acc = bp2[tid];
      for (int t = 0; t < 128; ++t) acc += bp1[t] * Wp2[t * 64 + tid];
      bc[tid] = acc;
    }
  }
}

// ---------------- merged dispatch: binA (blocks < ablocks) ∥ gemm1-unscaled (rest) -------------
// binA: bin (dst,src) by dst>>8, dense batched appends, entries packed 32b:
//       (dst&255)<<24 | src  (src < 2^24).
// gemm1: hbuf[row][128] = rne_bf16(x @ W1)  -- NO dis scaling (applied per-edge in gather1),
//        which removes the passB->gemm1 dependency and lets both phases share one dispatch.
__global__ __launch_bounds__(256) void k_bg(
    const int* __restrict__ src, const int* __restrict__ dst,
    uint32_t* __restrict__ binbuf, int* __restrict__ gcur, int E, int nbins, int ablocks,
    const float* __restrict__ A, const us* __restrict__ Wh, const us* __restrict__ Wl,
    us* __restrict__ out_bf16, int N, int ntiles) {
  __shared__ int smem[10240];                        // 40 KB union
  int tid = threadIdx.x;
  if ((int)blockIdx.x < ablocks) {
    // ---- binA ----
    uint2* stage = (uint2*)smem;                     // 4096 uint2 = 32 KB
    int* cnt   = smem + 8192;                        // 512
    int* base  = smem + 8704;                        // 512
    int* cur   = smem + 9216;                        // 512
    int* gbase = smem + 9728;                        // 512
    int e0 = blockIdx.x * EPB;
    int ne = min(EPB, E - e0);
    if (ne <= 0) return;
    cnt[tid] = 0; cnt[tid + 256] = 0;
    __syncthreads();
    for (int i = tid; i < ne; i += 256) atomicAdd(&cnt[dst[e0 + i] >> BIN_SHIFT], 1);
    __syncthreads();
    // exclusive scan cnt[512] -> base (wave 0, 8 chunks of 64)
    if (tid < 64) {
      int carry = 0;
#pragma unroll
      for (int c = 0; c < 8; ++c) {
        int v = cnt[c * 64 + tid];
        int incl = v;
#pragma unroll
        for (int off = 1; off < 64; off <<= 1) {
          int t = __shfl_up(incl, off, 64);
          if (tid >= off) incl += t;
        }
        base[c * 64 + tid] = carry + incl - v;
        carry += __shfl(incl, 63, 64);
      }
    }
    __syncthreads();
    for (int b = tid; b < nbins; b += 256)
      if (cnt[b] > 0) gbase[b] = atomicAdd(&gcur[b], cnt[b]);
    cur[tid] = base[tid]; cur[tid + 256] = base[tid + 256];
    __syncthreads();
    for (int i = tid; i < ne; i += 256) {
      int d = dst[e0 + i], s = src[e0 + i];
      int p = atomicAdd(&cur[d >> BIN_SHIFT], 1);
      stage[p] = make_uint2((unsigned)d, (unsigned)s);
    }
    __syncthreads();
    for (int i = tid; i < ne; i += 256) {
      uint2 en = stage[i];
      int b = en.x >> BIN_SHIFT;
      int gi = gbase[b] + (i - base[b]);
      if (gi < CAPB)
        binbuf[(size_t)b * CAPB + gi] = ((en.x & (BIN_NODES - 1)) << 24) | en.y;
    }
  } else {
    // ---- gemm1 (unscaled) ----
    us* As = (us*)smem;                              // 32*136 us = 8704 B
    int wave = tid >> 6, lane = tid & 63;
    int n0 = wave * 32;
    int nn = n0 + (lane & 31);
    int khalf = (lane >> 5) * 8;
    int m = lane & 31;

    short8 bh[8], bl[8];
#pragma unroll
    for (int c = 0; c < 8; ++c) {
      bh[c] = *(const short8*)&Wh[nn * 128 + c * 16 + khalf];
      bl[c] = *(const short8*)&Wl[nn * 128 + c * 16 + khalf];
    }

    int t0 = (int)blockIdx.x - ablocks;
    for (int t = t0; t < ntiles; t += G1GRID) {
      int row0 = t * 32;
      __syncthreads();
      for (int j = tid; j < 1024; j += 256) {
        int r = j >> 5, c = j & 31;
        int row = row0 + r;
        float4 v = make_float4(0.f, 0.f, 0.f, 0.f);
        if (row < N) v = *(const float4*)&A[(size_t)row * 128 + c * 4];
        *(ushort4*)&As[r * 136 + c * 4] = make_ushort4(
            f32_to_bf16_rne(v.x), f32_to_bf16_rne(v.y),
            f32_to_bf16_rne(v.z), f32_to_bf16_rne(v.w));
      }
      __syncthreads();

      f32x16 acc = {};
#pragma unroll
      for (int c = 0; c < 8; ++c) {
        short8 ah = *(const short8*)&As[m * 136 + c * 16 + khalf];
        acc = __builtin_amdgcn_mfma_f32_32x32x16_bf16(ah, bh[c], acc, 0, 0, 0);
        acc = __builtin_amdgcn_mfma_f32_32x32x16_bf16(ah, bl[c], acc, 0, 0, 0);
      }

      int colo = n0 + (lane & 31);
      int rbase = row0 + 4 * (lane >> 5);
#pragma unroll
      for (int reg = 0; reg < 16; ++reg) {
        int row = rbase + (reg & 3) + 8 * (reg >> 2);
        if (row < N)
          out_bf16[(size_t)row * 128 + colo] = f32_to_bf16_rne(acc[reg]);
      }
    }
  }
}

// ---------------- pass B: per-bin deg/dis/start + col fill from packed entries ----------------
__global__ __launch_bounds__(256) void k_passB(
    const uint32_t* __restrict__ binbuf, const int* __restrict__ gcur,
    int* __restrict__ deg, float* __restrict__ dis, int* __restrict__ start,
    int* __restrict__ col, int N, int nbins) {
  __shared__ int hist[256], lstart[256], cur[256];
  __shared__ int colstage[CAPB];                     // 24 KB
  __shared__ int binbase_s;
  int b = blockIdx.x, tid = threadIdx.x;
  int node0 = b << BIN_SHIFT;
  int cnt = min(gcur[b], CAPB);
  hist[tid] = 0;
  __syncthreads();
  const uint32_t* bp = binbuf + (size_t)b * CAPB;
  for (int i = tid; i < cnt; i += 256) atomicAdd(&hist[bp[i] >> 24], 1);
  __syncthreads();
  if (tid < 64) {
    // binbase = sum of capped counts of previous bins
    int s = 0;
    for (int i = tid; i < b; i += 64) s += min(gcur[i], CAPB);
#pragma unroll
    for (int off = 32; off; off >>= 1) s += __shfl_xor(s, off, 64);
    if (tid == 0) binbase_s = s;
    // exclusive scan hist[256] -> lstart (4 chunks of 64)
    int carry = 0;
#pragma unroll
    for (int c = 0; c < 4; ++c) {
      int v = hist[c * 64 + tid];
      int incl = v;
#pragma unroll
      for (int off = 1; off < 64; off <<= 1) {
        int t = __shfl_up(incl, off, 64);
        if (tid >= off) incl += t;
      }
      lstart[c * 64 + tid] = carry + incl - v;
      carry += __shfl(incl, 63, 64);
    }
  }
  __syncthreads();
  int binbase = binbase_s;
  {
    int node = node0 + tid;
    if (node < N) {
      int dg = hist[tid];
      deg[node] = dg;
      dis[node] = rsqrtf((float)(dg + 1));
      start[node] = binbase + lstart[tid];
    }
  }
  cur[tid] = lstart[tid];
  __syncthreads();
  for (int i = tid; i < cnt; i += 256) {
    uint32_t en = bp[i];
    int p = atomicAdd(&cur[en >> 24], 1);
    colstage[p] = (int)(en & 0xFFFFFFu);
  }
  __syncthreads();
  for (int i = tid; i < cnt; i += 256) col[binbase + i] = colstage[i];
}

// ---------------- gather layer 1: dis-weighted (h is UNSCALED x@W1) ----------------------------
// acc = sum_e dis[src_e]*h[src_e] + dis[node]*h[node];  act = relu(acc*dis[node] + b1).
// dis[col] preloaded per-lane alongside col; both broadcast via readlane.
__global__ __launch_bounds__(512) void k_gather1(
    const us* __restrict__ h, us* __restrict__ o,
    const int* __restrict__ start, const int* __restrict__ deg,
    const int* __restrict__ col, const float* __restrict__ dis,
    const float* __restrict__ bias, int N) {
  int wave = threadIdx.x >> 6, lane = threadIdx.x & 63;
  int node = blockIdx.x * 8 + wave;
  if (node >= N) return;
  const uint32_t* h1 = (const uint32_t*)h;
  float sc = dis[node];
  uint32_t u = h1[(size_t)node * 64 + lane];     // self row
  float a0 = sc * bflo(u), b0 = sc * bfhi(u);
  float a1 = 0.f, b1 = 0.f, a2 = 0.f, b2 = 0.f, a3 = 0.f, b3 = 0.f;
  float a4 = 0.f, b4 = 0.f, a5 = 0.f, b5 = 0.f, a6 = 0.f, b6 = 0.f, a7 = 0.f, b7 = 0.f;
  int e0 = start[node];
  int dg = deg[node];
  int myc = (lane < dg) ? col[e0 + lane] : N;    // N = zero row (dummy)
  float myd = (lane < dg) ? dis[myc] : 0.f;
  int dgm = min(dg, 64);
  for (int k = 0; k < dgm; k += 8) {
    int c0 = __builtin_amdgcn_readlane(myc, k);
    int c1 = __builtin_amdgcn_readlane(myc, k + 1);
    int c2 = __builtin_amdgcn_readlane(myc, k + 2);
    int c3 = __builtin_amdgcn_readlane(myc, k + 3);
    int c4 = __builtin_amdgcn_readlane(myc, k + 4);
    int c5 = __builtin_amdgcn_readlane(myc, k + 5);
    int c6 = __builtin_amdgcn_readlane(myc, k + 6);
    int c7 = __builtin_amdgcn_readlane(myc, k + 7);
    float d0 = rdlane_f(myd, k),     d1 = rdlane_f(myd, k + 1);
    float d2 = rdlane_f(myd, k + 2), d3 = rdlane_f(myd, k + 3);
    float d4 = rdlane_f(myd, k + 4), d5 = rdlane_f(myd, k + 5);
    float d6 = rdlane_f(myd, k + 6), d7 = rdlane_f(myd, k + 7);
    uint32_t u0 = h1[(size_t)c0 * 64 + lane];
    uint32_t u1 = h1[(size_t)c1 * 64 + lane];
    uint32_t u2 = h1[(size_t)c2 * 64 + lane];
    uint32_t u3 = h1[(size_t)c3 * 64 + lane];
    uint32_t u4 = h1[(size_t)c4 * 64 + lane];
    uint32_t u5 = h1[(size_t)c5 * 64 + lane];
    uint32_t u6 = h1[(size_t)c6 * 64 + lane];
    uint32_t u7 = h1[(size_t)c7 * 64 + lane];
    a0 += d0 * bflo(u0); b0 += d0 * bfhi(u0);
    a1 += d1 * bflo(u1); b1 += d1 * bfhi(u1);
    a2 += d2 * bflo(u2); b2 += d2 * bfhi(u2);
    a3 += d3 * bflo(u3); b3 += d3 * bfhi(u3);
    a4 += d4 * bflo(u4); b4 += d4 * bfhi(u4);
    a5 += d5 * bflo(u5); b5 += d5 * bfhi(u5);
    a6 += d6 * bflo(u6); b6 += d6 * bfhi(u6);
    a7 += d7 * bflo(u7); b7 += d7 * bfhi(u7);
  }
  // extremely rare deg > 64 fallback (Poisson mean 16)
  for (int e = e0 + 64; e < e0 + dg; ++e) {
    int c = col[e];
    float dd = dis[c];
    uint32_t u0 = h1[(size_t)c * 64 + lane];
    a0 += dd * bflo(u0); b0 += dd * bfhi(u0);
  }
  float2 bb = ((const float2*)bias)[lane];
  float ax = ((a0 + a1) + (a2 + a3)) + ((a4 + a5) + (a6 + a7));
  float ay = ((b0 + b1) + (b2 + b3)) + ((b4 + b5) + (b6 + b7));
  float rx = fmaxf(ax * sc + bb.x, 0.f);
  float ry = fmaxf(ay * sc + bb.y, 0.f);
  ((uint32_t*)o)[(size_t)node * 64 + lane] =
      ((uint32_t)f32_to_bf16_rne(ry) << 16) | f32_to_bf16_rne(rx);
}

// ---------------- layer-2 GEMM: hbuf[row][128] = rne_bf16(dis[row] * (act @ W2)) ----------------
__global__ __launch_bounds__(256) void k_gemm2(
    const us* __restrict__ A, const us* __restrict__ Wh,
    const us* __restrict__ Wl, const float* __restrict__ dis,
    us* __restrict__ out_bf16, int N, int ntiles) {
  __shared__ us As[32 * 136];
  int tid = threadIdx.x;
  int wave = tid >> 6, lane = tid & 63;
  int n0 = wave * 32;
  int nn = n0 + (lane & 31);
  int khalf = (lane >> 5) * 8;
  int m = lane & 31;

  short8 bh[8], bl[8];
#pragma unroll
  for (int c = 0; c < 8; ++c) {
    bh[c] = *(const short8*)&Wh[nn * 128 + c * 16 + khalf];
    bl[c] = *(const short8*)&Wl[nn * 128 + c * 16 + khalf];
  }

  for (int t = blockIdx.x; t < ntiles; t += gridDim.x) {
    int row0 = t * 32;
    __syncthreads();
    for (int j = tid; j < 512; j += 256) {
      int r = j >> 4, c = j & 15;
      int row = row0 + r;
      uint4 v = make_uint4(0u, 0u, 0u, 0u);
      if (row < N) v = *(const uint4*)&A[(size_t)row * 128 + c * 8];
      *(uint4*)&As[r * 136 + c * 8] = v;
    }
    __syncthreads();

    f32x16 acc = {};
#pragma unroll
    for (int c = 0; c < 8; ++c) {
      short8 ah = *(const short8*)&As[m * 136 + c * 16 + khalf];
      acc = __builtin_amdgcn_mfma_f32_32x32x16_bf16(ah, bh[c], acc, 0, 0, 0);
      acc = __builtin_amdgcn_mfma_f32_32x32x16_bf16(ah, bl[c], acc, 0, 0, 0);
    }

    int col = n0 + (lane & 31);
    int rbase = row0 + 4 * (lane >> 5);
#pragma unroll
    for (int reg = 0; reg < 16; ++reg) {
      int row = rbase + (reg & 3) + 8 * (reg >> 2);
      if (row < N) {
        float v = acc[reg] * dis[row];
        out_bf16[(size_t)row * 128 + col] = f32_to_bf16_rne(v);
      }
    }
  }
}

// ---------------- gather layer 2: h pre-scaled by dis[src] (unchanged champion path) -----------
__global__ __launch_bounds__(512) void k_gather(
    const us* __restrict__ h, us* __restrict__ o,
    const int* __restrict__ start, const int* __restrict__ deg,
    const int* __restrict__ col, const float* __restrict__ dis,
    const float* __restrict__ bias, int N) {
  int wave = threadIdx.x >> 6, lane = threadIdx.x & 63;
  int node = blockIdx.x * 8 + wave;
  if (node >= N) return;
  const uint32_t* h1 = (const uint32_t*)h;
  uint32_t u = h1[(size_t)node * 64 + lane];     // self row
  float a0 = bflo(u), b0 = bfhi(u);
  float a1 = 0.f, b1 = 0.f, a2 = 0.f, b2 = 0.f, a3 = 0.f, b3 = 0.f;
  float a4 = 0.f, b4 = 0.f, a5 = 0.f, b5 = 0.f, a6 = 0.f, b6 = 0.f, a7 = 0.f, b7 = 0.f;
  int e0 = start[node];
  int dg = deg[node];
  int myc = (lane < dg) ? col[e0 + lane] : N;    // N = zero row (dummy)
  int dgm = min(dg, 64);
  for (int k = 0; k < dgm; k += 8) {
    int c0 = __builtin_amdgcn_readlane(myc, k);
    int c1 = __builtin_amdgcn_readlane(myc, k + 1);
    int c2 = __builtin_amdgcn_readlane(myc, k + 2);
    int c3 = __builtin_amdgcn_readlane(myc, k + 3);
    int c4 = __builtin_amdgcn_readlane(myc, k + 4);
    int c5 = __builtin_amdgcn_readlane(myc, k + 5);
    int c6 = __builtin_amdgcn_readlane(myc, k + 6);
    int c7 = __builtin_amdgcn_readlane(myc, k + 7);
    uint32_t u0 = h1[(size_t)c0 * 64 + lane];
    uint32_t u1 = h1[(size_t)c1 * 64 + lane];
    uint32_t u2 = h1[(size_t)c2 * 64 + lane];
    uint32_t u3 = h1[(size_t)c3 * 64 + lane];
    uint32_t u4 = h1[(size_t)c4 * 64 + lane];
    uint32_t u5 = h1[(size_t)c5 * 64 + lane];
    uint32_t u6 = h1[(size_t)c6 * 64 + lane];
    uint32_t u7 = h1[(size_t)c7 * 64 + lane];
    a0 += bflo(u0); b0 += bfhi(u0);
    a1 += bflo(u1); b1 += bfhi(u1);
    a2 += bflo(u2); b2 += bfhi(u2);
    a3 += bflo(u3); b3 += bfhi(u3);
    a4 += bflo(u4); b4 += bfhi(u4);
    a5 += bflo(u5); b5 += bfhi(u5);
    a6 += bflo(u6); b6 += bfhi(u6);
    a7 += bflo(u7); b7 += bfhi(u7);
  }
  // extremely rare deg > 64 fallback (Poisson mean 16)
  for (int e = e0 + 64; e < e0 + dg; ++e) {
    uint32_t u0 = h1[(size_t)col[e] * 64 + lane];
    a0 += bflo(u0); b0 += bfhi(u0);
  }
  float sc = dis[node];
  float2 bb = ((const float2*)bias)[lane];
  float ax = ((a0 + a1) + (a2 + a3)) + ((a4 + a5) + (a6 + a7));
  float ay = ((b0 + b1) + (b2 + b3)) + ((b4 + b5) + (b6 + b7));
  float rx = fmaxf(ax * sc + bb.x, 0.f);
  float ry = fmaxf(ay * sc + bb.y, 0.f);
  ((uint32_t*)o)[(size_t)node * 64 + lane] =
      ((uint32_t)f32_to_bf16_rne(ry) << 16) | f32_to_bf16_rne(rx);
}

// ---------------- head: out = log_softmax(act @ Wc + bc) via MFMA, fused softmax ----------------
__global__ __launch_bounds__(256) void k_head_mfma(
    const us* __restrict__ act, const us* __restrict__ Wch,
    const us* __restrict__ Wcl, const float* __restrict__ bc,
    float* __restrict__ out, int N) {
  __shared__ us As[64 * 136];
  __shared__ float red[2][2][64];
  int tid = threadIdx.x;
  int wave = tid >> 6, lane = tid & 63;
  int rt = wave >> 1, ct = wave & 1;
  int colj = ct * 32 + (lane & 31);
  int khalf = (lane >> 5) * 8;
  int m = lane & 31;

  short8 bh[8], bl[8];
#pragma unroll
  for (int c = 0; c < 8; ++c) {
    bh[c] = *(const short8*)&Wch[colj * 128 + c * 16 + khalf];
    bl[c] = *(const short8*)&Wcl[colj * 128 + c * 16 + khalf];
  }

  int row0 = blockIdx.x * 64;
  for (int j = tid; j < 1024; j += 256) {
    int r = j >> 4, c = j & 15;
    int row = row0 + r;
    uint4 v = make_uint4(0u, 0u, 0u, 0u);
    if (row < N) v = *(const uint4*)&act[(size_t)row * 128 + c * 8];
    *(uint4*)&As[r * 136 + c * 8] = v;
  }
  __syncthreads();

  f32x16 acc = {};
  int mrow = rt * 32 + m;
#pragma unroll
  for (int c = 0; c < 8; ++c) {
    short8 ah = *(const short8*)&As[mrow * 136 + c * 16 + khalf];
    acc = __builtin_amdgcn_mfma_f32_32x32x16_bf16(ah, bh[c], acc, 0, 0, 0);
    acc = __builtin_amdgcn_mfma_f32_32x32x16_bf16(ah, bl[c], acc, 0, 0, 0);
  }

  float bcv = bc[colj];
  float lg[16], mx[16];
#pragma unroll
  for (int reg = 0; reg < 16; ++reg) {
    lg[reg] = acc[reg] + bcv;
    float v = lg[reg];
#pragma unroll
    for (int off = 16; off > 0; off >>= 1) v = fmaxf(v, __shfl_xor(v, off, 32));
    mx[reg] = v;
  }
  if ((lane & 31) == 0) {
#pragma unroll
    for (int reg = 0; reg < 16; ++reg) {
      int rl = rt * 32 + (reg & 3) + 8 * (reg >> 2) + 4 * (lane >> 5);
      red[0][ct][rl] = mx[reg];
    }
  }
  __syncthreads();

  float ex[16], sm[16];
#pragma unroll
  for (int reg = 0; reg < 16; ++reg) {
    int rl = rt * 32 + (reg & 3) + 8 * (reg >> 2) + 4 * (lane >> 5);
    float rmax = fmaxf(red[0][0][rl], red[0][1][rl]);
    ex[reg] = lg[reg] - rmax;
    float v = expf(ex[reg]);
#pragma unroll
    for (int off = 16; off > 0; off >>= 1) v += __shfl_xor(v, off, 32);
    sm[reg] = v;
  }
  if ((lane & 31) == 0) {
#pragma unroll
    for (int reg = 0; reg < 16; ++reg) {
      int rl = rt * 32 + (reg & 3) + 8 * (reg >> 2) + 4 * (lane >> 5);
      red[1][ct][rl] = sm[reg];
    }
  }
  __syncthreads();

#pragma unroll
  for (int reg = 0; reg < 16; ++reg) {
    int rl = rt * 32 + (reg & 3) + 8 * (reg >> 2) + 4 * (lane >> 5);
    int row = row0 + rl;
    if (row < N) {
      float total = red[1][0][rl] + red[1][1][rl];
      out[(size_t)row * 64 + colj] = ex[reg] - logf(total);
    }
  }
}

extern "C" void kernel_launch(void* const* d_in, const int* in_sizes, int n_in,
                              void* d_out, int out_size, void* d_ws, size_t ws_size,
                              hipStream_t stream) {
  const float* x   = (const float*)d_in[0];
  const int*   ei  = (const int*)d_in[1];
  const float* W1  = (const float*)d_in[2];
  const float* b1  = (const float*)d_in[3];
  const float* W2  = (const float*)d_in[4];
  const float* b2  = (const float*)d_in[5];
  const float* Wp1 = (const float*)d_in[6];
  const float* bp1 = (const float*)d_in[7];
  const float* Wp2 = (const float*)d_in[8];
  const float* bp2 = (const float*)d_in[9];
  float* out = (float*)d_out;

  int N = in_sizes[0] / 128;
  int E = in_sizes[1] / 2;
  const int* src = ei;
  const int* dst = ei + E;
  int nbins = (N + BIN_NODES - 1) >> BIN_SHIFT;

  // workspace layout (int granularity)
  float* dis   = (float*)d_ws;                    // N
  int*   deg   = (int*)(dis + N);                 // N
  int*   start = deg + N;                         // N
  int*   col   = start + N;                       // E
  int*   gcur  = col + ((E + 3) & ~3);            // 512 (zeroed by k_prep)
  us* Wt1h = (us*)(gcur + 512);                   // 16384 each
  us* Wt1l = Wt1h + 16384;
  us* Wt2h = Wt1l + 16384;
  us* Wt2l = Wt2h + 16384;
  us* Wch  = Wt2l + 16384;                        // 8192
  us* Wcl  = Wch + 8192;                          // 8192
  float* bc = (float*)(Wcl + 8192);               // 64 (+pad)
  uint32_t* binbuf = (uint32_t*)(bc + 80);        // nbins*CAPB packed u32 (~9.6 MB)
  us* hbuf = (us*)(binbuf + (size_t)nbins * CAPB);  // (N+1)*128 bf16 (row N = zero, by k_prep)
  us* act  = hbuf + (size_t)(N + 1) * 128;          // N*128 bf16 = 25.6 MB

  int ablocks = (E + EPB - 1) / EPB;
  int ntiles = (N + 31) / 32;
  int agblocks = (N + 7) / 8;
  int hblocks = (N + 63) / 64;

  // prep: weight transform + gcur/zero-row init
  k_prep<<<161, 256, 0, stream>>>(W1, W2, Wp1, Wp2, bp1, bp2,
                                  Wt1h, Wt1l, Wt2h, Wt2l, Wch, Wcl, bc,
                                  gcur, (int*)(hbuf + (size_t)N * 128));
  // merged: binA (edge binning) ∥ gemm1-unscaled (x @ W1)
  k_bg<<<ablocks + G1GRID, 256, 0, stream>>>(src, dst, binbuf, gcur, E, nbins, ablocks,
                                             x, Wt1h, Wt1l, hbuf, N, ntiles);
  k_passB<<<nbins, 256, 0, stream>>>(binbuf, gcur, deg, dis, start, col, N, nbins);

  // layer 1 aggregate (dis-weighted, since hbuf is unscaled)
  k_gather1<<<agblocks, 512, 0, stream>>>(hbuf, act, start, deg, col, dis, b1, N);
  // layer 2
  k_gemm2<<<ntiles < 1024 ? ntiles : 1024, 256, 0, stream>>>(act, Wt2h, Wt2l, dis, hbuf, N, ntiles);
  k_gather<<<agblocks, 512, 0, stream>>>(hbuf, act, start, deg, col, dis, b2, N);
  // folded head (MFMA + fused log_softmax)
  k_head_mfma<<<hblocks, 256, 0, stream>>>(act, Wch, Wcl, bc, out, N);
}